// Round 1
// baseline (684.416 us; speedup 1.0000x reference)
//
#include <hip/hip_runtime.h>
#include <hip/hip_bf16.h>
#include <stdint.h>

#define N_NODES 100000
#define NE      250000
#define SDIM    128
#define CDIM    768
#define HS      64
#define HC      192
#define TILE_E  32

typedef __attribute__((ext_vector_type(8))) short bf16x8;
typedef __attribute__((ext_vector_type(4))) float f32x4;

static __device__ __forceinline__ uint16_t f2bf(float f) {
    union { __hip_bfloat16 h; uint16_t u; } cv;
    cv.h = __float2bfloat16(f);
    return cv.u;
}

// ---------------- phase 0: W1c (768x192 f32) -> W1c^T (192x768 bf16) in ws ----
__global__ void k_convert_w(const float* __restrict__ W1c, uint16_t* __restrict__ W1cT) {
    const int tid = blockIdx.x * 256 + threadIdx.x;
    const int stride = gridDim.x * 256;
    for (int i = tid; i < HC * CDIM; i += stride) {
        const int n = i / CDIM, k = i - n * CDIM;   // write index = n*768 + k
        W1cT[i] = f2bf(W1c[k * HC + n]);
    }
}

// ---------------- structural path: exact f32, W1s staged in LDS --------------
__global__ __launch_bounds__(256, 3) void k_structural(
    const float* __restrict__ z, const int* __restrict__ edge,
    const float* __restrict__ W1s, const float* __restrict__ b1s,
    const float* __restrict__ W2s, const float* __restrict__ b2s,
    float* __restrict__ out)
{
    __shared__ float Wl[SDIM * HS];        // 32KB, row-major [128][64]
    __shared__ float Pl[TILE_E * 132];     // padded rows: bank-conflict-free broadcast

    const int t = threadIdx.x;
    const int e0 = blockIdx.x * TILE_E;

    // stage W1s (coalesced float4)
    {
        const float4* src = (const float4*)W1s;
        float4* dst = (float4*)Wl;
        for (int m = t; m < SDIM * HS / 4; m += 256) dst[m] = src[m];
    }
    // stage products z[s]*z[d] (8 threads per edge)
    {
        const int el = t >> 3, p = t & 7;
        const int e = e0 + el;
        if (e < NE) {
            const int s = edge[2 * e], d = edge[2 * e + 1];
            const float* rs = z + (long)s * SDIM;
            const float* rd = z + (long)d * SDIM;
            #pragma unroll
            for (int cc = 0; cc < 2; ++cc) {
                const int c = p + cc * 8;           // chunk of 8 floats
                float4 s0 = *(const float4*)(rs + c * 8);
                float4 s1 = *(const float4*)(rs + c * 8 + 4);
                float4 d0 = *(const float4*)(rd + c * 8);
                float4 d1 = *(const float4*)(rd + c * 8 + 4);
                float4 r0 = {s0.x * d0.x, s0.y * d0.y, s0.z * d0.z, s0.w * d0.w};
                float4 r1 = {s1.x * d1.x, s1.y * d1.y, s1.z * d1.z, s1.w * d1.w};
                *(float4*)(&Pl[el * 132 + c * 8]) = r0;
                *(float4*)(&Pl[el * 132 + c * 8 + 4]) = r1;
            }
        }
    }
    __syncthreads();

    // each thread: one edge (8 threads/edge), 8 hidden units
    const int el = t >> 3, p = t & 7;
    float h[8] = {0, 0, 0, 0, 0, 0, 0, 0};
    const float4* Wl4 = (const float4*)Wl;
    #pragma unroll 4
    for (int k = 0; k < SDIM; ++k) {
        const float pv = Pl[el * 132 + k];          // broadcast within 8-lane group
        float4 w0 = Wl4[k * 16 + p * 2];
        float4 w1 = Wl4[k * 16 + p * 2 + 1];
        h[0] += pv * w0.x; h[1] += pv * w0.y; h[2] += pv * w0.z; h[3] += pv * w0.w;
        h[4] += pv * w1.x; h[5] += pv * w1.y; h[6] += pv * w1.z; h[7] += pv * w1.w;
    }
    float partial = 0.f;
    #pragma unroll
    for (int j = 0; j < 8; ++j) {
        const int c = p * 8 + j;
        partial += fmaxf(h[j] + b1s[c], 0.f) * W2s[c];
    }
    partial += __shfl_xor(partial, 1);
    partial += __shfl_xor(partial, 2);
    partial += __shfl_xor(partial, 4);
    const int e = e0 + el;
    if (p == 0 && e < NE) out[e] = partial + b2s[0];
}

// ---------------- chemistry path: bf16 MFMA, K=768, N=192 --------------------
__global__ __launch_bounds__(256, 2) void k_chemistry(
    const float* __restrict__ chem, const int* __restrict__ edge,
    const float* __restrict__ smask, const uint16_t* __restrict__ W1cT,
    const float* __restrict__ b1c, const float* __restrict__ W2c,
    const float* __restrict__ b2c, const float* __restrict__ alphap,
    float* __restrict__ out)
{
    __shared__ uint16_t Albs[TILE_E * CDIM];   // 48KB, XOR-swizzled rows of 1536B
    __shared__ uint16_t Btl[HC * 64];          // 24KB, W1c^T chunk [192][64], swizzled

    const int t = threadIdx.x;
    const int e0 = blockIdx.x * TILE_E;

    // ---- stage A: bf16(c[s]*c[d]) for 32 edges, full K=768 ----
    {
        const int el = t >> 3, p = t & 7;
        const int e = e0 + el;
        if (e < NE) {
            const int s = edge[2 * e], d = edge[2 * e + 1];
            const float* rs = chem + (long)s * CDIM;
            const float* rd = chem + (long)d * CDIM;
            #pragma unroll
            for (int j = 0; j < 12; ++j) {
                const int c = p + j * 8;            // 16B chunk id 0..95
                float4 s0 = *(const float4*)(rs + c * 8);
                float4 s1 = *(const float4*)(rs + c * 8 + 4);
                float4 d0 = *(const float4*)(rd + c * 8);
                float4 d1 = *(const float4*)(rd + c * 8 + 4);
                union { uint16_t u[8]; int4 v; } pk;
                pk.u[0] = f2bf(s0.x * d0.x); pk.u[1] = f2bf(s0.y * d0.y);
                pk.u[2] = f2bf(s0.z * d0.z); pk.u[3] = f2bf(s0.w * d0.w);
                pk.u[4] = f2bf(s1.x * d1.x); pk.u[5] = f2bf(s1.y * d1.y);
                pk.u[6] = f2bf(s1.z * d1.z); pk.u[7] = f2bf(s1.w * d1.w);
                const int bo = el * (CDIM * 2) + ((c * 16) ^ ((el & 7) << 4));
                *(int4*)((char*)Albs + bo) = pk.v;
            }
        }
    }

    const int lane = t & 63, wid = t >> 6;
    const int wr = wid >> 1, wc = wid & 1;
    const int lr = lane & 15, lg = lane >> 4;

    f32x4 acc[6];
    #pragma unroll
    for (int i = 0; i < 6; ++i) acc[i] = (f32x4){0.f, 0.f, 0.f, 0.f};

    for (int kc = 0; kc < 12; ++kc) {
        __syncthreads();
        // stage B^T chunk: Btl[n][kl] = W1c[kc*64+kl][n], coalesced from W1cT
        for (int m = t; m < 1536; m += 256) {
            const int n = m >> 3, c = m & 7;
            int4 v = *(const int4*)(W1cT + n * CDIM + kc * 64 + c * 8);
            *(int4*)((char*)Btl + n * 128 + ((c * 16) ^ ((n & 7) << 4))) = v;
        }
        __syncthreads();
        #pragma unroll
        for (int ks = 0; ks < 2; ++ks) {
            const int kl = ks * 32 + lg * 8;        // 0..63 within chunk
            const int kg = kc * 64 + kl;
            const int ar = wr * 16 + lr;
            bf16x8 af = *(const bf16x8*)((const char*)Albs +
                        ar * (CDIM * 2) + ((kg * 2) ^ ((ar & 7) << 4)));
            #pragma unroll
            for (int fi = 0; fi < 6; ++fi) {
                const int n = wc * 96 + fi * 16 + lr;
                bf16x8 bv = *(const bf16x8*)((const char*)Btl +
                            n * 128 + ((kl * 2) ^ ((n & 7) << 4)));
                acc[fi] = __builtin_amdgcn_mfma_f32_16x16x32_bf16(af, bv, acc[fi], 0, 0, 0);
            }
        }
    }

    __syncthreads();
    float* hbuf = (float*)Albs;                    // 32 x 192 f32 = 24KB (fits in 48KB)
    #pragma unroll
    for (int fi = 0; fi < 6; ++fi) {
        const int col = wc * 96 + fi * 16 + lr;
        #pragma unroll
        for (int r = 0; r < 4; ++r) {
            const int row = wr * 16 + lg * 4 + r;  // verified C/D layout
            hbuf[row * HC + col] = acc[fi][r];
        }
    }
    __syncthreads();

    {
        const int el = t >> 3, p = t & 7;
        float partial = 0.f;
        #pragma unroll
        for (int j = 0; j < 24; ++j) {
            const int c = p * 24 + j;
            partial += fmaxf(hbuf[el * HC + c] + b1c[c], 0.f) * W2c[c];
        }
        partial += __shfl_xor(partial, 1);
        partial += __shfl_xor(partial, 2);
        partial += __shfl_xor(partial, 4);
        const int e = e0 + el;
        if (p == 0 && e < NE) {
            const int s = edge[2 * e], d = edge[2 * e + 1];
            const float valid = smask[s] * smask[d];
            out[e] += alphap[0] * valid * (partial + b2c[0]);
        }
    }
}

extern "C" void kernel_launch(void* const* d_in, const int* in_sizes, int n_in,
                              void* d_out, int out_size, void* d_ws, size_t ws_size,
                              hipStream_t stream)
{
    const float* z     = (const float*)d_in[0];
    const float* chem  = (const float*)d_in[1];
    const int*   edge  = (const int*)d_in[2];
    const float* smask = (const float*)d_in[3];
    const float* W1s   = (const float*)d_in[4];
    const float* b1s   = (const float*)d_in[5];
    const float* W2s   = (const float*)d_in[6];
    const float* b2s   = (const float*)d_in[7];
    const float* W1c   = (const float*)d_in[8];
    const float* b1c   = (const float*)d_in[9];
    const float* W2c   = (const float*)d_in[10];
    const float* b2c   = (const float*)d_in[11];
    const float* alpha = (const float*)d_in[12];
    float* out = (float*)d_out;

    uint16_t* W1cT = (uint16_t*)d_ws;   // 294912 bytes

    k_convert_w<<<dim3(64), dim3(256), 0, stream>>>(W1c, W1cT);

    const int grid = (NE + TILE_E - 1) / TILE_E;   // 7813
    k_structural<<<dim3(grid), dim3(256), 0, stream>>>(z, edge, W1s, b1s, W2s, b2s, out);
    k_chemistry<<<dim3(grid), dim3(256), 0, stream>>>(chem, edge, smask, W1cT,
                                                      b1c, W2c, b2c, alpha, out);
}

// Round 2
// 682.775 us; speedup vs baseline: 1.0024x; 1.0024x over previous
//
#include <hip/hip_runtime.h>
#include <hip/hip_bf16.h>
#include <stdint.h>

#define N_NODES 100000
#define NE      250000
#define SDIM    128
#define CDIM    768
#define HS      64
#define HC      192
#define TILE_E  32
#define NBLK    ((NE + TILE_E - 1) / TILE_E)

typedef __attribute__((ext_vector_type(8))) short bf16x8;
typedef __attribute__((ext_vector_type(4))) float f32x4;

static __device__ __forceinline__ uint16_t f2bf(float f) {
    union { __hip_bfloat16 h; uint16_t u; } cv;
    cv.h = __float2bfloat16(f);
    return cv.u;
}
static __device__ __forceinline__ float bf2f(uint16_t u) {
    union { float f; uint32_t i; } cv; cv.i = ((uint32_t)u) << 16; return cv.f;
}

// ---------------- phase 0: W1c (768x192 f32) -> W1c^T (192x768 bf16) ---------
__global__ void k_convert_w(const float* __restrict__ W1c, uint16_t* __restrict__ W1cT) {
    const int tid = blockIdx.x * 256 + threadIdx.x;
    const int stride = gridDim.x * 256;
    for (int i = tid; i < HC * CDIM; i += stride) {
        const int n = i / CDIM, k = i - n * CDIM;
        W1cT[i] = f2bf(W1c[k * HC + n]);
    }
}

// ------- structural path (exact f32) + chem-table bf16 conversion tail -------
__global__ __launch_bounds__(256, 3) void k_structural(
    const float* __restrict__ z, const int* __restrict__ edge,
    const float* __restrict__ W1s, const float* __restrict__ b1s,
    const float* __restrict__ W2s, const float* __restrict__ b2s,
    float* __restrict__ out,
    const float* __restrict__ chem, uint16_t* __restrict__ chem_bf, long conv_n)
{
    __shared__ float Wl[SDIM * HS];        // 32KB
    __shared__ float Pl[TILE_E * 132];     // padded rows

    const int t = threadIdx.x;
    const int e0 = blockIdx.x * TILE_E;

    {
        const float4* src = (const float4*)W1s;
        float4* dst = (float4*)Wl;
        for (int m = t; m < SDIM * HS / 4; m += 256) dst[m] = src[m];
    }
    {
        const int el = t >> 3, p = t & 7;
        const int e = e0 + el;
        if (e < NE) {
            const int s = edge[2 * e], d = edge[2 * e + 1];
            const float* rs = z + (long)s * SDIM;
            const float* rd = z + (long)d * SDIM;
            #pragma unroll
            for (int cc = 0; cc < 2; ++cc) {
                const int c = p + cc * 8;
                float4 s0 = *(const float4*)(rs + c * 8);
                float4 s1 = *(const float4*)(rs + c * 8 + 4);
                float4 d0 = *(const float4*)(rd + c * 8);
                float4 d1 = *(const float4*)(rd + c * 8 + 4);
                float4 r0 = {s0.x * d0.x, s0.y * d0.y, s0.z * d0.z, s0.w * d0.w};
                float4 r1 = {s1.x * d1.x, s1.y * d1.y, s1.z * d1.z, s1.w * d1.w};
                *(float4*)(&Pl[el * 132 + c * 8]) = r0;
                *(float4*)(&Pl[el * 132 + c * 8 + 4]) = r1;
            }
        }
    }
    __syncthreads();

    const int el = t >> 3, p = t & 7;
    float h[8] = {0, 0, 0, 0, 0, 0, 0, 0};
    const float4* Wl4 = (const float4*)Wl;
    #pragma unroll 4
    for (int k = 0; k < SDIM; ++k) {
        const float pv = Pl[el * 132 + k];
        float4 w0 = Wl4[k * 16 + p * 2];
        float4 w1 = Wl4[k * 16 + p * 2 + 1];
        h[0] += pv * w0.x; h[1] += pv * w0.y; h[2] += pv * w0.z; h[3] += pv * w0.w;
        h[4] += pv * w1.x; h[5] += pv * w1.y; h[6] += pv * w1.z; h[7] += pv * w1.w;
    }
    float partial = 0.f;
    #pragma unroll
    for (int j = 0; j < 8; ++j) {
        const int c = p * 8 + j;
        partial += fmaxf(h[j] + b1s[c], 0.f) * W2s[c];
    }
    partial += __shfl_xor(partial, 1);
    partial += __shfl_xor(partial, 2);
    partial += __shfl_xor(partial, 4);
    const int e = e0 + el;
    if (p == 0 && e < NE) out[e] = partial + b2s[0];

    // ---- chem f32 -> bf16 conversion tail (grid-stride, streaming) ----
    {
        const long base = ((long)blockIdx.x * 256 + t) * 8;
        const long stride = (long)gridDim.x * 256 * 8;
        for (long i = base; i < conv_n; i += stride) {
            float4 a = *(const float4*)(chem + i);
            float4 b = *(const float4*)(chem + i + 4);
            union { uint16_t u[8]; int4 v; } pk;
            pk.u[0] = f2bf(a.x); pk.u[1] = f2bf(a.y);
            pk.u[2] = f2bf(a.z); pk.u[3] = f2bf(a.w);
            pk.u[4] = f2bf(b.x); pk.u[5] = f2bf(b.y);
            pk.u[6] = f2bf(b.z); pk.u[7] = f2bf(b.w);
            *(int4*)(chem_bf + i) = pk.v;
        }
    }
}

// ---------------- chemistry path: bf16 MFMA, barrier-light -------------------
template<bool BF16TAB>
__global__ __launch_bounds__(256, 3) void k_chem(
    const void* __restrict__ chemv, const int* __restrict__ edge,
    const float* __restrict__ smask, const uint16_t* __restrict__ W1cT,
    const float* __restrict__ b1c, const float* __restrict__ W2c,
    const float* __restrict__ b2c, const float* __restrict__ alphap,
    float* __restrict__ out)
{
    __shared__ uint16_t Albs[TILE_E * CDIM];   // 48KB, XOR-swizzled 1536B rows

    const int t = threadIdx.x;
    const int e0 = blockIdx.x * TILE_E;

    // ---- stage A: bf16(c[s]*c[d]) for 32 edges, full K=768 ----
    {
        const int el = t >> 3, p = t & 7;
        const int e = e0 + el;
        if (e < NE) {
            const int s = edge[2 * e], d = edge[2 * e + 1];
            if constexpr (BF16TAB) {
                const uint16_t* rs = (const uint16_t*)chemv + (long)s * CDIM;
                const uint16_t* rd = (const uint16_t*)chemv + (long)d * CDIM;
                #pragma unroll
                for (int half = 0; half < 2; ++half) {
                    int4 ls[6], ld_[6];
                    #pragma unroll
                    for (int j = 0; j < 6; ++j)
                        ls[j] = *(const int4*)(rs + (p + (half * 6 + j) * 8) * 8);
                    #pragma unroll
                    for (int j = 0; j < 6; ++j)
                        ld_[j] = *(const int4*)(rd + (p + (half * 6 + j) * 8) * 8);
                    #pragma unroll
                    for (int j = 0; j < 6; ++j) {
                        union { int4 v; uint16_t u[8]; } a, b, r;
                        a.v = ls[j]; b.v = ld_[j];
                        #pragma unroll
                        for (int q = 0; q < 8; ++q)
                            r.u[q] = f2bf(bf2f(a.u[q]) * bf2f(b.u[q]));
                        const int c = p + (half * 6 + j) * 8;
                        const int bo = el * (CDIM * 2) + ((c * 16) ^ ((el & 7) << 4));
                        *(int4*)((char*)Albs + bo) = r.v;
                    }
                }
            } else {
                const float* rs = (const float*)chemv + (long)s * CDIM;
                const float* rd = (const float*)chemv + (long)d * CDIM;
                #pragma unroll
                for (int j = 0; j < 12; ++j) {
                    const int c = p + j * 8;
                    float4 s0 = *(const float4*)(rs + c * 8);
                    float4 s1 = *(const float4*)(rs + c * 8 + 4);
                    float4 d0 = *(const float4*)(rd + c * 8);
                    float4 d1 = *(const float4*)(rd + c * 8 + 4);
                    union { uint16_t u[8]; int4 v; } pk;
                    pk.u[0] = f2bf(s0.x * d0.x); pk.u[1] = f2bf(s0.y * d0.y);
                    pk.u[2] = f2bf(s0.z * d0.z); pk.u[3] = f2bf(s0.w * d0.w);
                    pk.u[4] = f2bf(s1.x * d1.x); pk.u[5] = f2bf(s1.y * d1.y);
                    pk.u[6] = f2bf(s1.z * d1.z); pk.u[7] = f2bf(s1.w * d1.w);
                    const int bo = el * (CDIM * 2) + ((c * 16) ^ ((el & 7) << 4));
                    *(int4*)((char*)Albs + bo) = pk.v;
                }
            }
        }
    }
    __syncthreads();

    // ---- K loop: A from LDS, B straight from L2 (W1cT hot), no barriers ----
    const int lane = t & 63, wid = t >> 6;
    const int wr = wid >> 1, wc = wid & 1;
    const int lr = lane & 15, lg = lane >> 4;
    const int ar = wr * 16 + lr;
    const char* Arow = (const char*)Albs + ar * (CDIM * 2);
    const int swz = (ar & 7) << 4;
    const uint16_t* Bbase = W1cT + (long)(wc * 96 + lr) * CDIM + lg * 8;

    f32x4 acc[6];
    #pragma unroll
    for (int i = 0; i < 6; ++i) acc[i] = (f32x4){0.f, 0.f, 0.f, 0.f};

    #pragma unroll 4
    for (int kc = 0; kc < 24; ++kc) {
        const int kg = kc * 32 + lg * 8;
        bf16x8 af = *(const bf16x8*)(Arow + ((kg * 2) ^ swz));
        #pragma unroll
        for (int fi = 0; fi < 6; ++fi) {
            bf16x8 bv = *(const bf16x8*)(Bbase + fi * (16 * CDIM) + kc * 32);
            acc[fi] = __builtin_amdgcn_mfma_f32_16x16x32_bf16(af, bv, acc[fi], 0, 0, 0);
        }
    }

    __syncthreads();
    float* hbuf = (float*)Albs;                    // 32 x 192 f32 = 24KB
    #pragma unroll
    for (int fi = 0; fi < 6; ++fi) {
        const int col = wc * 96 + fi * 16 + lr;
        #pragma unroll
        for (int r = 0; r < 4; ++r) {
            const int row = wr * 16 + lg * 4 + r;
            hbuf[row * HC + col] = acc[fi][r];
        }
    }
    __syncthreads();

    {
        const int el = t >> 3, p = t & 7;
        float partial = 0.f;
        #pragma unroll
        for (int j = 0; j < 24; ++j) {
            const int c = p * 24 + j;
            partial += fmaxf(hbuf[el * HC + c] + b1c[c], 0.f) * W2c[c];
        }
        partial += __shfl_xor(partial, 1);
        partial += __shfl_xor(partial, 2);
        partial += __shfl_xor(partial, 4);
        const int e = e0 + el;
        if (p == 0 && e < NE) {
            const int s = edge[2 * e], d = edge[2 * e + 1];
            const float valid = smask[s] * smask[d];
            out[e] += alphap[0] * valid * (partial + b2c[0]);
        }
    }
}

extern "C" void kernel_launch(void* const* d_in, const int* in_sizes, int n_in,
                              void* d_out, int out_size, void* d_ws, size_t ws_size,
                              hipStream_t stream)
{
    const float* z     = (const float*)d_in[0];
    const float* chem  = (const float*)d_in[1];
    const int*   edge  = (const int*)d_in[2];
    const float* smask = (const float*)d_in[3];
    const float* W1s   = (const float*)d_in[4];
    const float* b1s   = (const float*)d_in[5];
    const float* W2s   = (const float*)d_in[6];
    const float* b2s   = (const float*)d_in[7];
    const float* W1c   = (const float*)d_in[8];
    const float* b1c   = (const float*)d_in[9];
    const float* W2c   = (const float*)d_in[10];
    const float* b2c   = (const float*)d_in[11];
    const float* alpha = (const float*)d_in[12];
    float* out = (float*)d_out;

    uint16_t* W1cT   = (uint16_t*)d_ws;                  // 294912 B
    uint16_t* chemBf = (uint16_t*)d_ws + (size_t)HC * CDIM;
    const size_t need = (size_t)HC * CDIM * 2 + (size_t)N_NODES * CDIM * 2;
    const bool useBf = ws_size >= need;
    const long conv_n = useBf ? (long)N_NODES * CDIM : 0;

    k_convert_w<<<dim3(64), dim3(256), 0, stream>>>(W1c, W1cT);

    k_structural<<<dim3(NBLK), dim3(256), 0, stream>>>(
        z, edge, W1s, b1s, W2s, b2s, out, chem, chemBf, conv_n);

    if (useBf)
        k_chem<true><<<dim3(NBLK), dim3(256), 0, stream>>>(
            (const void*)chemBf, edge, smask, W1cT, b1c, W2c, b2c, alpha, out);
    else
        k_chem<false><<<dim3(NBLK), dim3(256), 0, stream>>>(
            (const void*)chem, edge, smask, W1cT, b1c, W2c, b2c, alpha, out);
}

// Round 4
// 402.321 us; speedup vs baseline: 1.7012x; 1.6971x over previous
//
#include <hip/hip_runtime.h>
#include <hip/hip_bf16.h>
#include <stdint.h>

#define N_NODES 100000
#define NE      250000
#define SDIM    128
#define CDIM    768
#define HS      64
#define HC      192
#define TILE_E  32
#define NBLK    ((NE + TILE_E - 1) / TILE_E)

#define CT      16                 // edges per chem tile
#define NT      (NE / CT)          // 15625 tiles (exact)
#define CBLK    256                // persistent chem blocks (1/CU)

typedef __attribute__((ext_vector_type(8))) short bf16x8;
typedef __attribute__((ext_vector_type(4))) float f32x4;

static __device__ __forceinline__ uint16_t f2bf(float f) {
    union { __hip_bfloat16 h; uint16_t u; } cv;
    cv.h = __float2bfloat16(f);
    return cv.u;
}
static __device__ __forceinline__ float bf2f(uint16_t u) {
    union { float f; uint32_t i; } cv; cv.i = ((uint32_t)u) << 16; return cv.f;
}

// ---------------- phase 0: W1c (768x192 f32) -> W1c^T (192x768 bf16) ---------
__global__ void k_convert_w(const float* __restrict__ W1c, uint16_t* __restrict__ W1cT) {
    const int tid = blockIdx.x * 256 + threadIdx.x;
    const int stride = gridDim.x * 256;
    for (int i = tid; i < HC * CDIM; i += stride) {
        const int n = i / CDIM, k = i - n * CDIM;
        W1cT[i] = f2bf(W1c[k * HC + n]);
    }
}

// ------- structural path (exact f32) + chem-table bf16 conversion tail -------
__global__ __launch_bounds__(256, 3) void k_structural(
    const float* __restrict__ z, const int* __restrict__ edge,
    const float* __restrict__ W1s, const float* __restrict__ b1s,
    const float* __restrict__ W2s, const float* __restrict__ b2s,
    float* __restrict__ out,
    const float* __restrict__ chem, uint16_t* __restrict__ chem_bf, long conv_n)
{
    __shared__ float Wl[SDIM * HS];
    __shared__ float Pl[TILE_E * 132];

    const int t = threadIdx.x;
    const int e0 = blockIdx.x * TILE_E;

    {
        const float4* src = (const float4*)W1s;
        float4* dst = (float4*)Wl;
        for (int m = t; m < SDIM * HS / 4; m += 256) dst[m] = src[m];
    }
    {
        const int el = t >> 3, p = t & 7;
        const int e = e0 + el;
        if (e < NE) {
            const int s = edge[2 * e], d = edge[2 * e + 1];
            const float* rs = z + (long)s * SDIM;
            const float* rd = z + (long)d * SDIM;
            #pragma unroll
            for (int cc = 0; cc < 2; ++cc) {
                const int c = p + cc * 8;
                float4 s0 = *(const float4*)(rs + c * 8);
                float4 s1 = *(const float4*)(rs + c * 8 + 4);
                float4 d0 = *(const float4*)(rd + c * 8);
                float4 d1 = *(const float4*)(rd + c * 8 + 4);
                float4 r0 = {s0.x * d0.x, s0.y * d0.y, s0.z * d0.z, s0.w * d0.w};
                float4 r1 = {s1.x * d1.x, s1.y * d1.y, s1.z * d1.z, s1.w * d1.w};
                *(float4*)(&Pl[el * 132 + c * 8]) = r0;
                *(float4*)(&Pl[el * 132 + c * 8 + 4]) = r1;
            }
        }
    }
    __syncthreads();

    const int el = t >> 3, p = t & 7;
    float h[8] = {0, 0, 0, 0, 0, 0, 0, 0};
    const float4* Wl4 = (const float4*)Wl;
    #pragma unroll 4
    for (int k = 0; k < SDIM; ++k) {
        const float pv = Pl[el * 132 + k];
        float4 w0 = Wl4[k * 16 + p * 2];
        float4 w1 = Wl4[k * 16 + p * 2 + 1];
        h[0] += pv * w0.x; h[1] += pv * w0.y; h[2] += pv * w0.z; h[3] += pv * w0.w;
        h[4] += pv * w1.x; h[5] += pv * w1.y; h[6] += pv * w1.z; h[7] += pv * w1.w;
    }
    float partial = 0.f;
    #pragma unroll
    for (int j = 0; j < 8; ++j) {
        const int c = p * 8 + j;
        partial += fmaxf(h[j] + b1s[c], 0.f) * W2s[c];
    }
    partial += __shfl_xor(partial, 1);
    partial += __shfl_xor(partial, 2);
    partial += __shfl_xor(partial, 4);
    const int e = e0 + el;
    if (p == 0 && e < NE) out[e] = partial + b2s[0];

    // ---- chem f32 -> bf16 conversion tail (grid-stride, streaming) ----
    {
        const long base = ((long)blockIdx.x * 256 + t) * 8;
        const long stride = (long)gridDim.x * 256 * 8;
        for (long i = base; i < conv_n; i += stride) {
            float4 a = *(const float4*)(chem + i);
            float4 b = *(const float4*)(chem + i + 4);
            union { uint16_t u[8]; int4 v; } pk;
            pk.u[0] = f2bf(a.x); pk.u[1] = f2bf(a.y);
            pk.u[2] = f2bf(a.z); pk.u[3] = f2bf(a.w);
            pk.u[4] = f2bf(b.x); pk.u[5] = f2bf(b.y);
            pk.u[6] = f2bf(b.z); pk.u[7] = f2bf(b.w);
            *(int4*)(chem_bf + i) = pk.v;
        }
    }
}

// ---------------- chemistry: persistent, B-in-registers ----------------------
static __device__ __forceinline__ void cvt_store_bf(uint16_t* Abuf, int el, int ch,
                                                    int4 vs, int4 vd) {
    union { int4 v; uint16_t u[8]; } a, b, r;
    a.v = vs; b.v = vd;
    #pragma unroll
    for (int q = 0; q < 8; ++q) r.u[q] = f2bf(bf2f(a.u[q]) * bf2f(b.u[q]));
    const int byte = el * 1536 + ((ch * 16) ^ ((el & 7) << 4));
    *(int4*)((char*)Abuf + byte) = r.v;
}
static __device__ __forceinline__ void stage_f32(uint16_t* Abuf, int el, int ch,
                                                 const float* rs, const float* rd) {
    float4 a0 = *(const float4*)(rs + ch * 8);
    float4 a1 = *(const float4*)(rs + ch * 8 + 4);
    float4 b0 = *(const float4*)(rd + ch * 8);
    float4 b1 = *(const float4*)(rd + ch * 8 + 4);
    union { int4 v; uint16_t u[8]; } r;
    r.u[0] = f2bf(a0.x * b0.x); r.u[1] = f2bf(a0.y * b0.y);
    r.u[2] = f2bf(a0.z * b0.z); r.u[3] = f2bf(a0.w * b0.w);
    r.u[4] = f2bf(a1.x * b1.x); r.u[5] = f2bf(a1.y * b1.y);
    r.u[6] = f2bf(a1.z * b1.z); r.u[7] = f2bf(a1.w * b1.w);
    const int byte = el * 1536 + ((ch * 16) ^ ((el & 7) << 4));
    *(int4*)((char*)Abuf + byte) = r.v;
}

template<bool BF16TAB>
__global__ __launch_bounds__(768, 3) void k_chem_persist(
    const void* __restrict__ chemv, const int* __restrict__ edge,
    const float* __restrict__ smask, const uint16_t* __restrict__ W1cT,
    const float* __restrict__ b1c, const float* __restrict__ W2c,
    const float* __restrict__ b2c, const float* __restrict__ alphap,
    float* __restrict__ out)
{
    __shared__ uint16_t A[2][CT * CDIM];   // 2 x 24KB, XOR-swizzled rows
    __shared__ float part[2][CT][13];

    const int t = threadIdx.x;
    const int w = t >> 6, lane = t & 63, lr = lane & 15, lg = lane >> 4;
    const int b = blockIdx.x;

    // tile range for this block: first 9 blocks get 62 tiles, rest 61
    const int t0 = b * 61 + (b < 9 ? b : 9);
    const int t1 = t0 + 61 + (b < 9 ? 1 : 0);

    // ---- B slice into registers (once): cols [16w, 16w+16), full K ----
    bf16x8 Breg[24];
    {
        const uint16_t* Bp = W1cT + (long)(w * 16 + lr) * CDIM + lg * 8;
        #pragma unroll
        for (int kc = 0; kc < 24; ++kc)
            Breg[kc] = *(const bf16x8*)(Bp + kc * 32);
    }
    const float b1 = b1c[w * 16 + lr];
    const float w2 = W2c[w * 16 + lr];
    const float alpha = alphap[0], b2 = b2c[0];

    // staging slot decomposition: 1536 16B-slots, 2 per thread
    const int el0 = t / 96,          ch0 = t % 96;
    const int el1 = (t + 768) / 96,  ch1 = (t + 768) % 96;

    const uint16_t* chemB = (const uint16_t*)chemv;
    const float*    chemF = (const float*)chemv;

    // ---- stage first tile ----
    {
        const int ea = t0 * CT + el0, eb = t0 * CT + el1;
        const int sa = edge[2 * ea], da = edge[2 * ea + 1];
        const int sb = edge[2 * eb], db = edge[2 * eb + 1];
        if constexpr (BF16TAB) {
            int4 vsa = *(const int4*)(chemB + (long)sa * CDIM + ch0 * 8);
            int4 vda = *(const int4*)(chemB + (long)da * CDIM + ch0 * 8);
            int4 vsb = *(const int4*)(chemB + (long)sb * CDIM + ch1 * 8);
            int4 vdb = *(const int4*)(chemB + (long)db * CDIM + ch1 * 8);
            cvt_store_bf(A[t0 & 1], el0, ch0, vsa, vda);
            cvt_store_bf(A[t0 & 1], el1, ch1, vsb, vdb);
        } else {
            stage_f32(A[t0 & 1], el0, ch0, chemF + (long)sa * CDIM, chemF + (long)da * CDIM);
            stage_f32(A[t0 & 1], el1, ch1, chemF + (long)sb * CDIM, chemF + (long)db * CDIM);
        }
    }
    __syncthreads();

    const int rowbase = lr * 1536;           // A-row byte base
    const int swz = (lr & 7) << 4;           // within-row slot swizzle (matches write)

    for (int ti = t0; ti < t1; ++ti) {
        const int cur = ti & 1;
        const bool pf = (ti + 1 < t1);

        // 1. issue next tile's gathers early (latency hidden under MFMA)
        int4 vsa, vda, vsb, vdb;
        if (BF16TAB && pf) {
            const int ea = (ti + 1) * CT + el0, eb = (ti + 1) * CT + el1;
            const int sa = edge[2 * ea], da = edge[2 * ea + 1];
            const int sb = edge[2 * eb], db = edge[2 * eb + 1];
            vsa = *(const int4*)(chemB + (long)sa * CDIM + ch0 * 8);
            vda = *(const int4*)(chemB + (long)da * CDIM + ch0 * 8);
            vsb = *(const int4*)(chemB + (long)sb * CDIM + ch1 * 8);
            vdb = *(const int4*)(chemB + (long)db * CDIM + ch1 * 8);
        }

        // 2. finalize previous tile (wave 0, 16 lanes)
        if (ti > t0 && t < CT) {
            const int e = (ti - 1) * CT + t;
            float s = 0.f;
            #pragma unroll
            for (int ww = 0; ww < 12; ++ww) s += part[(ti - 1) & 1][t][ww];
            const int si = edge[2 * e], di = edge[2 * e + 1];
            out[e] += alpha * smask[si] * smask[di] * (s + b2);
        }

        // 3. compute: 24 x (ds_read + MFMA), 4 independent acc chains
        f32x4 acc0 = {0,0,0,0}, acc1 = {0,0,0,0}, acc2 = {0,0,0,0}, acc3 = {0,0,0,0};
        {
            const char* Ab = (const char*)A[cur];
            #pragma unroll
            for (int j = 0; j < 6; ++j) {
                const int k0 = j, k1 = 6 + j, k2 = 12 + j, k3 = 18 + j;
                bf16x8 a0 = *(const bf16x8*)(Ab + rowbase + ((k0 * 64 + lg * 16) ^ swz));
                bf16x8 a1 = *(const bf16x8*)(Ab + rowbase + ((k1 * 64 + lg * 16) ^ swz));
                bf16x8 a2 = *(const bf16x8*)(Ab + rowbase + ((k2 * 64 + lg * 16) ^ swz));
                bf16x8 a3 = *(const bf16x8*)(Ab + rowbase + ((k3 * 64 + lg * 16) ^ swz));
                acc0 = __builtin_amdgcn_mfma_f32_16x16x32_bf16(a0, Breg[k0], acc0, 0, 0, 0);
                acc1 = __builtin_amdgcn_mfma_f32_16x16x32_bf16(a1, Breg[k1], acc1, 0, 0, 0);
                acc2 = __builtin_amdgcn_mfma_f32_16x16x32_bf16(a2, Breg[k2], acc2, 0, 0, 0);
                acc3 = __builtin_amdgcn_mfma_f32_16x16x32_bf16(a3, Breg[k3], acc3, 0, 0, 0);
            }
        }

        // 4. relu + col-dot + 16-lane reduce -> per-edge partial for this wave
        {
            float p0 = fmaxf(acc0[0] + acc1[0] + acc2[0] + acc3[0] + b1, 0.f) * w2;
            float p1 = fmaxf(acc0[1] + acc1[1] + acc2[1] + acc3[1] + b1, 0.f) * w2;
            float p2 = fmaxf(acc0[2] + acc1[2] + acc2[2] + acc3[2] + b1, 0.f) * w2;
            float p3 = fmaxf(acc0[3] + acc1[3] + acc2[3] + acc3[3] + b1, 0.f) * w2;
            #pragma unroll
            for (int m = 1; m <= 8; m <<= 1) {
                p0 += __shfl_xor(p0, m);
                p1 += __shfl_xor(p1, m);
                p2 += __shfl_xor(p2, m);
                p3 += __shfl_xor(p3, m);
            }
            if (lr == 0) {
                part[cur][lg * 4 + 0][w] = p0;
                part[cur][lg * 4 + 1][w] = p1;
                part[cur][lg * 4 + 2][w] = p2;
                part[cur][lg * 4 + 3][w] = p3;
            }
        }

        // 5. write staged next tile into the other A buffer
        if (pf) {
            if constexpr (BF16TAB) {
                cvt_store_bf(A[cur ^ 1], el0, ch0, vsa, vda);
                cvt_store_bf(A[cur ^ 1], el1, ch1, vsb, vdb);
            } else {
                const int ea = (ti + 1) * CT + el0, eb = (ti + 1) * CT + el1;
                const int sa = edge[2 * ea], da = edge[2 * ea + 1];
                const int sb = edge[2 * eb], db = edge[2 * eb + 1];
                stage_f32(A[cur ^ 1], el0, ch0, chemF + (long)sa * CDIM, chemF + (long)da * CDIM);
                stage_f32(A[cur ^ 1], el1, ch1, chemF + (long)sb * CDIM, chemF + (long)db * CDIM);
            }
        }
        __syncthreads();
    }

    // final tile's scores
    if (t < CT) {
        const int e = (t1 - 1) * CT + t;
        float s = 0.f;
        #pragma unroll
        for (int ww = 0; ww < 12; ++ww) s += part[(t1 - 1) & 1][t][ww];
        const int si = edge[2 * e], di = edge[2 * e + 1];
        out[e] += alpha * smask[si] * smask[di] * (s + b2);
    }
}

extern "C" void kernel_launch(void* const* d_in, const int* in_sizes, int n_in,
                              void* d_out, int out_size, void* d_ws, size_t ws_size,
                              hipStream_t stream)
{
    const float* z     = (const float*)d_in[0];
    const float* chem  = (const float*)d_in[1];
    const int*   edge  = (const int*)d_in[2];
    const float* smask = (const float*)d_in[3];
    const float* W1s   = (const float*)d_in[4];
    const float* b1s   = (const float*)d_in[5];
    const float* W2s   = (const float*)d_in[6];
    const float* b2s   = (const float*)d_in[7];
    const float* W1c   = (const float*)d_in[8];
    const float* b1c   = (const float*)d_in[9];
    const float* W2c   = (const float*)d_in[10];
    const float* b2c   = (const float*)d_in[11];
    const float* alpha = (const float*)d_in[12];
    float* out = (float*)d_out;

    uint16_t* W1cT   = (uint16_t*)d_ws;                  // 294912 B
    uint16_t* chemBf = (uint16_t*)d_ws + (size_t)HC * CDIM;
    const size_t need = (size_t)HC * CDIM * 2 + (size_t)N_NODES * CDIM * 2;
    const bool useBf = ws_size >= need;
    const long conv_n = useBf ? (long)N_NODES * CDIM : 0;

    k_convert_w<<<dim3(64), dim3(256), 0, stream>>>(W1c, W1cT);

    k_structural<<<dim3(NBLK), dim3(256), 0, stream>>>(
        z, edge, W1s, b1s, W2s, b2s, out, chem, chemBf, conv_n);

    if (useBf)
        k_chem_persist<true><<<dim3(CBLK), dim3(768), 0, stream>>>(
            (const void*)chemBf, edge, smask, W1cT, b1c, W2c, b2c, alpha, out);
    else
        k_chem_persist<false><<<dim3(CBLK), dim3(768), 0, stream>>>(
            (const void*)chem, edge, smask, W1cT, b1c, W2c, b2c, alpha, out);
}